// Round 7
// baseline (89.582 us; speedup 1.0000x reference)
//
#include <hip/hip_runtime.h>
#include <float.h>

static constexpr int H    = 2048;
static constexpr int Wd   = 2048;
static constexpr int NPIX = H * Wd;
static constexpr int BT   = 256;               // threads per block
static constexpr int NB   = 1024;              // 4 blocks/CU capacity-guaranteed
static constexpr int N4   = NPIX / 4;
static constexpr int ITER = N4 / (NB * BT);    // == 4, exact

// ws layout: ws_u[0]=arrival counter, ws_u[1]=ratio-as-bits flag (0 = not ready),
// both zeroed by an 8-byte memset node each call. Partials (f32) start at
// ws_u+4 (16B aligned): p[s*NB + b], s in [0,12).
// slots: [0..2] sparse min {x*z, y*z, z} (unscaled), [3..5] sparse max,
//        [6..8] dense min, [9..11] dense max.

__global__ __launch_bounds__(BT, 4) void fused_depth_scale_kernel(
    const float* __restrict__ dense,
    const float* __restrict__ sparse,
    const int*   __restrict__ mask,
    const float* __restrict__ intr,
    unsigned int* __restrict__ ws_u,
    float* __restrict__ out)
{
    float* partials = (float*)(ws_u + 4);
    const float cx = intr[2], cy = intr[3];
    const float qnan = __uint_as_float(0x7FC00000u);

    const float4* d4 = (const float4*)dense;
    const float4* s4 = (const float4*)sparse;
    const int4*   m4 = (const int4*)mask;

    const int tid = blockIdx.x * BT + threadIdx.x;

    float loc[12];
#pragma unroll
    for (int s = 0; s < 12; ++s) loc[s] = ((s % 6) < 3) ? FLT_MAX : -FLT_MAX;

    // ---- Phase 1: batched loads; dense stays in registers through the sync ----
    int4   mv[ITER];
    float4 sv[ITER];
    float4 dv[ITER];
#pragma unroll
    for (int k = 0; k < ITER; ++k) {
        const int i = tid + k * (NB * BT);
        mv[k] = m4[i];
        sv[k] = s4[i];
        dv[k] = d4[i];
    }

#pragma unroll
    for (int k = 0; k < ITER; ++k) {
        const int i = tid + k * (NB * BT);
        const int base = i << 2;                 // 2048 % 4 == 0: row never split
        const float yc = (float)(base >> 11) - cy;
        const float xf = (float)(base & 2047);
        const int   mm[4] = { mv[k].x, mv[k].y, mv[k].z, mv[k].w };
        const float dd[4] = { dv[k].x, dv[k].y, dv[k].z, dv[k].w };
        const float ss[4] = { sv[k].x, sv[k].y, sv[k].z, sv[k].w };
#pragma unroll
        for (int j = 0; j < 4; ++j) {
            // NaN sentinel: v_min/v_max (IEEE) return the non-NaN operand.
            float sd = (mm[j] != 0) ? ss[j] : qnan;
            float de = (mm[j] != 0) ? dd[j] : qnan;
            float xc = xf + (float)j - cx;
            float spx = xc * sd;
            float spy = yc * sd;
            float dpx = xc * de;
            float dpy = yc * de;
            loc[0] = fminf(loc[0], spx); loc[3]  = fmaxf(loc[3],  spx);
            loc[1] = fminf(loc[1], spy); loc[4]  = fmaxf(loc[4],  spy);
            loc[2] = fminf(loc[2], sd ); loc[5]  = fmaxf(loc[5],  sd );
            loc[6] = fminf(loc[6], dpx); loc[9]  = fmaxf(loc[9],  dpx);
            loc[7] = fminf(loc[7], dpy); loc[10] = fmaxf(loc[10], dpy);
            loc[8] = fminf(loc[8], de ); loc[11] = fmaxf(loc[11], de );
        }
    }

    // wave-64 butterfly
#pragma unroll
    for (int off = 32; off > 0; off >>= 1) {
#pragma unroll
        for (int s = 0; s < 12; ++s) {
            float o = __shfl_xor(loc[s], off, 64);
            loc[s] = ((s % 6) < 3) ? fminf(loc[s], o) : fmaxf(loc[s], o);
        }
    }

    __shared__ float red[4][12];
    __shared__ float rs;
    __shared__ unsigned int last_sh;
    const int lane = threadIdx.x & 63;
    const int wid  = threadIdx.x >> 6;
    if (lane == 0) {
#pragma unroll
        for (int s = 0; s < 12; ++s) red[wid][s] = loc[s];
    }
    __syncthreads();

    // publish per-block partials: relaxed agent-scope (write-through, no wbl2)
    if (threadIdx.x < 12) {
        const int s = threadIdx.x;
        const bool is_min = (s % 6) < 3;
        float v = red[0][s];
#pragma unroll
        for (int w = 1; w < 4; ++w)
            v = is_min ? fminf(v, red[w][s]) : fmaxf(v, red[w][s]);
        __hip_atomic_store(&partials[s * NB + blockIdx.x], v,
                           __ATOMIC_RELAXED, __HIP_MEMORY_SCOPE_AGENT);
    }
    __syncthreads();   // vmcnt drain: partials acked at coherence point

    // ---- arrival; last block finalizes ----
    if (threadIdx.x == 0) {
        unsigned int old = __hip_atomic_fetch_add(&ws_u[0], 1u,
                               __ATOMIC_ACQ_REL, __HIP_MEMORY_SCOPE_AGENT);
        last_sh = (old == (unsigned)(NB - 1)) ? 1u : 0u;
    }
    __syncthreads();

    if (last_sh) {
        __builtin_amdgcn_fence(__ATOMIC_ACQUIRE, "agent");
        // reduce 12 x NB partials: exactly one float4 per thread per slot
        static_assert(NB / 4 == BT, "one float4 per thread per slot");
        const float4* p4 = (const float4*)partials;
        float loc2[12];
#pragma unroll
        for (int s = 0; s < 12; ++s) {
            float4 p = p4[s * BT + threadIdx.x];
            if ((s % 6) < 3)
                loc2[s] = fminf(fminf(p.x, p.y), fminf(p.z, p.w));
            else
                loc2[s] = fmaxf(fmaxf(p.x, p.y), fmaxf(p.z, p.w));
        }
#pragma unroll
        for (int off = 32; off > 0; off >>= 1) {
#pragma unroll
            for (int s = 0; s < 12; ++s) {
                float o = __shfl_xor(loc2[s], off, 64);
                loc2[s] = ((s % 6) < 3) ? fminf(loc2[s], o) : fmaxf(loc2[s], o);
            }
        }
        if (lane == 0) {
#pragma unroll
            for (int s = 0; s < 12; ++s) red[wid][s] = loc2[s];
        }
        __syncthreads();
        if (threadIdx.x == 0) {
            float fin[12];
#pragma unroll
            for (int s = 0; s < 12; ++s) {
                const bool is_min = (s % 6) < 3;
                float v = red[0][s];
#pragma unroll
                for (int w = 1; w < 4; ++w)
                    v = is_min ? fminf(v, red[w][s]) : fmaxf(v, red[w][s]);
                fin[s] = v;
            }
            const float inv_fx = 1.0f / intr[0], inv_fy = 1.0f / intr[1];
            float sx = (fin[3]  - fin[0]) * inv_fx;
            float sy = (fin[4]  - fin[1]) * inv_fy;
            float sz =  fin[5]  - fin[2];
            float dx = (fin[9]  - fin[6]) * inv_fx;
            float dy = (fin[10] - fin[7]) * inv_fy;
            float dz =  fin[11] - fin[8];
            float ratio = sqrtf(sx*sx + sy*sy + sz*sz) /
                          sqrtf(dx*dx + dy*dy + dz*dz);
            rs = ratio;
            out[NPIX] = 1.0f;  // std
            // publish ratio AS the flag value (never 0 for valid input)
            __hip_atomic_store(&ws_u[1], __float_as_uint(ratio),
                               __ATOMIC_RELEASE, __HIP_MEMORY_SCOPE_AGENT);
        }
        __syncthreads();
    } else {
        if (threadIdx.x == 0) {
            // RELAXED polls (no cache-invalidate storm) + sleep backoff;
            // the loaded value IS the ratio -> no acquire needed.
            unsigned int fb;
            int polls = 0;
            while ((fb = __hip_atomic_load(&ws_u[1], __ATOMIC_RELAXED,
                                           __HIP_MEMORY_SCOPE_AGENT)) == 0u) {
                if (polls < 8) __builtin_amdgcn_s_sleep(2);   // ~0.05 us
                else           __builtin_amdgcn_s_sleep(16);  // ~0.43 us
                ++polls;
            }
            rs = __uint_as_float(fb);
        }
        __syncthreads();
    }

    // ---- Phase 3: scale register-held dense, store ----
    const float r = rs;
    float4* o4 = (float4*)out;
#pragma unroll
    for (int k = 0; k < ITER; ++k) {
        const int i = tid + k * (NB * BT);
        float4 v = dv[k];
        o4[i] = make_float4(v.x * r, v.y * r, v.z * r, v.w * r);
    }
}

extern "C" void kernel_launch(void* const* d_in, const int* in_sizes, int n_in,
                              void* d_out, int out_size, void* d_ws, size_t ws_size,
                              hipStream_t stream) {
    const float* dense  = (const float*)d_in[0];  // depth_estimations
    const float* sparse = (const float*)d_in[1];  // sparse_depths
    const int*   mask   = (const int*)d_in[2];    // sparse_depth_masks
    const float* intr   = (const float*)d_in[3];  // intrinsics

    float*        out  = (float*)d_out;
    unsigned int* ws_u = (unsigned int*)d_ws;

    hipMemsetAsync((void*)ws_u, 0, 2 * sizeof(unsigned int), stream);
    fused_depth_scale_kernel<<<NB, BT, 0, stream>>>(dense, sparse, mask, intr,
                                                    ws_u, out);
}

// Round 9
// 75.269 us; speedup vs baseline: 1.1901x; 1.1901x over previous
//
#include <hip/hip_runtime.h>
#include <float.h>

static constexpr int H    = 2048;
static constexpr int Wd   = 2048;
static constexpr int NPIX = H * Wd;
static constexpr int BT   = 256;                 // threads per block
static constexpr int N4   = NPIX / 4;

static constexpr int NB1   = 2048;               // stage-1 blocks: 8/CU
static constexpr int ITER1 = N4 / (NB1 * BT);    // == 2, exact
static constexpr int NB2   = 2048;               // stage-2 blocks
static constexpr int ITER2 = N4 / (NB2 * BT);    // == 2, exact

typedef float f32x4 __attribute__((ext_vector_type(4)));  // native vec for builtins

// ws layout: ws_u[0] = arrival counter (memset to 0 each call),
//            ws_u[1..3] = pad, partials (f32) start at ws_u+4:
//            p[s*NB1 + b], s in [0,12); ratio at p + 12*NB1.
// slots: [0..2] sparse min {x*z, y*z, z} (unscaled), [3..5] sparse max,
//        [6..8] dense min, [9..11] dense max.

__global__ __launch_bounds__(BT, 8) void reduce_bbox_kernel(
    const float* __restrict__ dense,
    const float* __restrict__ sparse,
    const int*   __restrict__ mask,
    const float* __restrict__ intr,
    unsigned int* __restrict__ ws_u)
{
    float* partials = (float*)(ws_u + 4);
    float* ratio_p  = partials + 12 * NB1;

    const float cx = intr[2], cy = intr[3];
    const float qnan = __uint_as_float(0x7FC00000u);

    const float4* d4 = (const float4*)dense;
    const float4* s4 = (const float4*)sparse;
    const int4*   m4 = (const int4*)mask;

    const int tid = blockIdx.x * BT + threadIdx.x;

    float loc[12];
#pragma unroll
    for (int s = 0; s < 12; ++s) loc[s] = ((s % 6) < 3) ? FLT_MAX : -FLT_MAX;

    // batched loads: all 6 vector loads in flight, then consume
    int4   mv[ITER1];
    float4 sv[ITER1];
    float4 dv[ITER1];
#pragma unroll
    for (int k = 0; k < ITER1; ++k) {
        const int i = tid + k * (NB1 * BT);
        mv[k] = m4[i];
        sv[k] = s4[i];
        dv[k] = d4[i];
    }

#pragma unroll
    for (int k = 0; k < ITER1; ++k) {
        const int i = tid + k * (NB1 * BT);
        const int base = i << 2;                 // 2048 % 4 == 0: row never split
        const float yc = (float)(base >> 11) - cy;
        const float xf = (float)(base & 2047);
        const int   mm[4] = { mv[k].x, mv[k].y, mv[k].z, mv[k].w };
        const float dd[4] = { dv[k].x, dv[k].y, dv[k].z, dv[k].w };
        const float ss[4] = { sv[k].x, sv[k].y, sv[k].z, sv[k].w };
#pragma unroll
        for (int j = 0; j < 4; ++j) {
            // NaN sentinel: v_min/v_max (IEEE) return the non-NaN operand,
            // so masked-out pixels are no-ops -> branchless.
            float sd = (mm[j] != 0) ? ss[j] : qnan;
            float de = (mm[j] != 0) ? dd[j] : qnan;
            float xc = xf + (float)j - cx;
            float spx = xc * sd;
            float spy = yc * sd;
            float dpx = xc * de;
            float dpy = yc * de;
            loc[0] = fminf(loc[0], spx); loc[3]  = fmaxf(loc[3],  spx);
            loc[1] = fminf(loc[1], spy); loc[4]  = fmaxf(loc[4],  spy);
            loc[2] = fminf(loc[2], sd ); loc[5]  = fmaxf(loc[5],  sd );
            loc[6] = fminf(loc[6], dpx); loc[9]  = fmaxf(loc[9],  dpx);
            loc[7] = fminf(loc[7], dpy); loc[10] = fmaxf(loc[10], dpy);
            loc[8] = fminf(loc[8], de ); loc[11] = fmaxf(loc[11], de );
        }
    }

    // wave-64 butterfly
#pragma unroll
    for (int off = 32; off > 0; off >>= 1) {
#pragma unroll
        for (int s = 0; s < 12; ++s) {
            float o = __shfl_xor(loc[s], off, 64);
            loc[s] = ((s % 6) < 3) ? fminf(loc[s], o) : fmaxf(loc[s], o);
        }
    }

    __shared__ float red[4][12];
    __shared__ unsigned int last_sh;
    const int lane = threadIdx.x & 63;
    const int wid  = threadIdx.x >> 6;
    if (lane == 0) {
#pragma unroll
        for (int s = 0; s < 12; ++s) red[wid][s] = loc[s];
    }
    __syncthreads();

    // publish per-block partials cross-XCD: agent-scope write-through
    if (threadIdx.x < 12) {
        const int s = threadIdx.x;
        const bool is_min = (s % 6) < 3;
        float v = red[0][s];
#pragma unroll
        for (int w = 1; w < 4; ++w)
            v = is_min ? fminf(v, red[w][s]) : fmaxf(v, red[w][s]);
        __hip_atomic_store(&partials[s * NB1 + blockIdx.x], v,
                           __ATOMIC_RELAXED, __HIP_MEMORY_SCOPE_AGENT);
    }
    __syncthreads();   // vmcnt drain: partials acked at coherence point

    if (threadIdx.x == 0) {
        unsigned int old = __hip_atomic_fetch_add(&ws_u[0], 1u,
                               __ATOMIC_ACQ_REL, __HIP_MEMORY_SCOPE_AGENT);
        last_sh = (old == (unsigned)(NB1 - 1)) ? 1u : 0u;
    }
    __syncthreads();

    if (!last_sh) return;   // non-last blocks exit; no polling anywhere

    // ---- last-arriving block: finalize (proven pattern from R7) ----
    __builtin_amdgcn_fence(__ATOMIC_ACQUIRE, "agent");

    static_assert(NB1 / 4 == 2 * BT, "two float4 per thread per slot");
    const float4* p4 = (const float4*)partials;
    float loc2[12];
#pragma unroll
    for (int s = 0; s < 12; ++s) {
        float4 a = p4[s * (NB1 / 4) + threadIdx.x];
        float4 b = p4[s * (NB1 / 4) + BT + threadIdx.x];
        if ((s % 6) < 3)
            loc2[s] = fminf(fminf(fminf(a.x, a.y), fminf(a.z, a.w)),
                            fminf(fminf(b.x, b.y), fminf(b.z, b.w)));
        else
            loc2[s] = fmaxf(fmaxf(fmaxf(a.x, a.y), fmaxf(a.z, a.w)),
                            fmaxf(fmaxf(b.x, b.y), fmaxf(b.z, b.w)));
    }
#pragma unroll
    for (int off = 32; off > 0; off >>= 1) {
#pragma unroll
        for (int s = 0; s < 12; ++s) {
            float o = __shfl_xor(loc2[s], off, 64);
            loc2[s] = ((s % 6) < 3) ? fminf(loc2[s], o) : fmaxf(loc2[s], o);
        }
    }
    if (lane == 0) {
#pragma unroll
        for (int s = 0; s < 12; ++s) red[wid][s] = loc2[s];
    }
    __syncthreads();

    if (threadIdx.x == 0) {
        float fin[12];
#pragma unroll
        for (int s = 0; s < 12; ++s) {
            const bool is_min = (s % 6) < 3;
            float v = red[0][s];
#pragma unroll
            for (int w = 1; w < 4; ++w)
                v = is_min ? fminf(v, red[w][s]) : fmaxf(v, red[w][s]);
            fin[s] = v;
        }
        const float inv_fx = 1.0f / intr[0], inv_fy = 1.0f / intr[1];
        float sx = (fin[3]  - fin[0]) * inv_fx;
        float sy = (fin[4]  - fin[1]) * inv_fy;
        float sz =  fin[5]  - fin[2];
        float dx = (fin[9]  - fin[6]) * inv_fx;
        float dy = (fin[10] - fin[7]) * inv_fy;
        float dz =  fin[11] - fin[8];
        float ratio = sqrtf(sx*sx + sy*sy + sz*sz) /
                      sqrtf(dx*dx + dy*dy + dz*dz);
        // agent store -> visible at LLC for k2's atomic load
        __hip_atomic_store(ratio_p, ratio,
                           __ATOMIC_RELEASE, __HIP_MEMORY_SCOPE_AGENT);
    }
}

// Stage 2: pure streaming scale. Ratio picked up once per block from LLC.
__global__ __launch_bounds__(BT) void scale_kernel(
    const float* __restrict__ dense,
    const float* __restrict__ ratio_p,
    float* __restrict__ out)
{
    const int tid = blockIdx.x * BT + threadIdx.x;
    const f32x4* d4 = (const f32x4*)dense;

    // dense loads in flight before the ratio sync
    f32x4 v0 = d4[tid];
    f32x4 v1 = d4[tid + NB2 * BT];

    __shared__ float rs;
    if (threadIdx.x == 0) {
        // agent-scope load: reads through to the coherence point (k1's store)
        rs = __hip_atomic_load(ratio_p, __ATOMIC_RELAXED,
                               __HIP_MEMORY_SCOPE_AGENT);
    }
    __syncthreads();
    const float r = rs;

    f32x4* o4 = (f32x4*)out;
    f32x4 r0 = v0 * r;
    f32x4 r1 = v1 * r;
    // nontemporal: don't evict L3-resident inputs with output lines
    __builtin_nontemporal_store(r0, &o4[tid]);
    __builtin_nontemporal_store(r1, &o4[tid + NB2 * BT]);
    if (blockIdx.x == 0 && threadIdx.x == 0) out[NPIX] = 1.0f;  // std
}

extern "C" void kernel_launch(void* const* d_in, const int* in_sizes, int n_in,
                              void* d_out, int out_size, void* d_ws, size_t ws_size,
                              hipStream_t stream) {
    const float* dense  = (const float*)d_in[0];  // depth_estimations
    const float* sparse = (const float*)d_in[1];  // sparse_depths
    const int*   mask   = (const int*)d_in[2];    // sparse_depth_masks
    const float* intr   = (const float*)d_in[3];  // intrinsics

    float*        out   = (float*)d_out;
    unsigned int* ws_u  = (unsigned int*)d_ws;
    float*        ratio = (float*)(ws_u + 4) + 12 * NB1;

    (void)hipMemsetAsync((void*)ws_u, 0, sizeof(unsigned int), stream);
    reduce_bbox_kernel<<<NB1, BT, 0, stream>>>(dense, sparse, mask, intr, ws_u);
    scale_kernel<<<NB2, BT, 0, stream>>>(dense, ratio, out);
}

// Round 10
// 23.954 us; speedup vs baseline: 3.7397x; 3.1422x over previous
//
#include <hip/hip_runtime.h>
#include <float.h>

static constexpr int H    = 2048;
static constexpr int Wd   = 2048;
static constexpr int NPIX = H * Wd;
static constexpr int BT   = 256;                 // threads per block
static constexpr int N4   = NPIX / 4;

static constexpr int NB1   = 2048;               // stage-1 blocks: 8/CU, 32 waves/CU
static constexpr int ITER1 = N4 / (NB1 * BT);    // == 2, exact
static constexpr int NB2   = 2048;               // stage-3 blocks
static constexpr int ITER2 = N4 / (NB2 * BT);    // == 2, exact

typedef float f32x4 __attribute__((ext_vector_type(4)));  // native vec for nt builtins

// ws layout (floats, SoA, NO atomics/counters anywhere):
//   partials p[s*NB1 + b], s in [0,12)  -- all rewritten every call
//   ratio at p + 12*NB1                 -- rewritten every call by finalize
// slots: [0..2] sparse min {x*z, y*z, z} (unscaled by 1/fx,1/fy),
//        [3..5] sparse max, [6..8] dense min, [9..11] dense max.
// Cross-kernel visibility: plain stores + kernel-boundary ordering
// (proven R2/R3/R6; all in-kernel cross-XCD sync variants cost 40-80us).

__global__ __launch_bounds__(BT) void reduce_bbox_kernel(
    const float* __restrict__ dense,
    const float* __restrict__ sparse,
    const int*   __restrict__ mask,
    const float* __restrict__ intr,
    float* __restrict__ ws)
{
    const float cx = intr[2], cy = intr[3];
    const float qnan = __uint_as_float(0x7FC00000u);

    const float4* d4 = (const float4*)dense;
    const float4* s4 = (const float4*)sparse;
    const int4*   m4 = (const int4*)mask;

    const int tid = blockIdx.x * BT + threadIdx.x;

    float loc[12];
#pragma unroll
    for (int s = 0; s < 12; ++s) loc[s] = ((s % 6) < 3) ? FLT_MAX : -FLT_MAX;

    // batched loads: all 6 vector loads in flight, then consume
    int4   mv[ITER1];
    float4 sv[ITER1];
    float4 dv[ITER1];
#pragma unroll
    for (int k = 0; k < ITER1; ++k) {
        const int i = tid + k * (NB1 * BT);
        mv[k] = m4[i];
        sv[k] = s4[i];
        dv[k] = d4[i];
    }

#pragma unroll
    for (int k = 0; k < ITER1; ++k) {
        const int i = tid + k * (NB1 * BT);
        const int base = i << 2;                 // 2048 % 4 == 0: row never split
        const float yc = (float)(base >> 11) - cy;
        const float xf = (float)(base & 2047);
        const int   mm[4] = { mv[k].x, mv[k].y, mv[k].z, mv[k].w };
        const float dd[4] = { dv[k].x, dv[k].y, dv[k].z, dv[k].w };
        const float ss[4] = { sv[k].x, sv[k].y, sv[k].z, sv[k].w };
#pragma unroll
        for (int j = 0; j < 4; ++j) {
            // NaN sentinel: v_min/v_max (IEEE) return the non-NaN operand,
            // so masked-out pixels are no-ops -> branchless.
            float sd = (mm[j] != 0) ? ss[j] : qnan;
            float de = (mm[j] != 0) ? dd[j] : qnan;
            float xc = xf + (float)j - cx;
            float spx = xc * sd;
            float spy = yc * sd;
            float dpx = xc * de;
            float dpy = yc * de;
            loc[0] = fminf(loc[0], spx); loc[3]  = fmaxf(loc[3],  spx);
            loc[1] = fminf(loc[1], spy); loc[4]  = fmaxf(loc[4],  spy);
            loc[2] = fminf(loc[2], sd ); loc[5]  = fmaxf(loc[5],  sd );
            loc[6] = fminf(loc[6], dpx); loc[9]  = fmaxf(loc[9],  dpx);
            loc[7] = fminf(loc[7], dpy); loc[10] = fmaxf(loc[10], dpy);
            loc[8] = fminf(loc[8], de ); loc[11] = fmaxf(loc[11], de );
        }
    }

    // wave-64 butterfly
#pragma unroll
    for (int off = 32; off > 0; off >>= 1) {
#pragma unroll
        for (int s = 0; s < 12; ++s) {
            float o = __shfl_xor(loc[s], off, 64);
            loc[s] = ((s % 6) < 3) ? fminf(loc[s], o) : fmaxf(loc[s], o);
        }
    }

    __shared__ float red[4][12];
    const int lane = threadIdx.x & 63;
    const int wid  = threadIdx.x >> 6;
    if (lane == 0) {
#pragma unroll
        for (int s = 0; s < 12; ++s) red[wid][s] = loc[s];
    }
    __syncthreads();

    if (threadIdx.x < 12) {
        const int s = threadIdx.x;
        const bool is_min = (s % 6) < 3;
        float v = red[0][s];
#pragma unroll
        for (int w = 1; w < 4; ++w)
            v = is_min ? fminf(v, red[w][s]) : fmaxf(v, red[w][s]);
        ws[s * NB1 + blockIdx.x] = v;   // plain store, no atomics
    }
}

// Stage 2 (1 block): reduce 12 x NB1 partials, publish ratio + std.
__global__ __launch_bounds__(BT) void finalize_kernel(
    const float* __restrict__ ws,
    const float* __restrict__ intr,
    float* __restrict__ ratio_p,
    float* __restrict__ out)
{
    static_assert(NB1 / 4 == 2 * BT, "two float4 per thread per slot");
    const float4* p4 = (const float4*)ws;
    float loc[12];
#pragma unroll
    for (int s = 0; s < 12; ++s) {
        float4 a = p4[s * (NB1 / 4) + threadIdx.x];
        float4 b = p4[s * (NB1 / 4) + BT + threadIdx.x];
        if ((s % 6) < 3)
            loc[s] = fminf(fminf(fminf(a.x, a.y), fminf(a.z, a.w)),
                           fminf(fminf(b.x, b.y), fminf(b.z, b.w)));
        else
            loc[s] = fmaxf(fmaxf(fmaxf(a.x, a.y), fmaxf(a.z, a.w)),
                           fmaxf(fmaxf(b.x, b.y), fmaxf(b.z, b.w)));
    }

#pragma unroll
    for (int off = 32; off > 0; off >>= 1) {
#pragma unroll
        for (int s = 0; s < 12; ++s) {
            float o = __shfl_xor(loc[s], off, 64);
            loc[s] = ((s % 6) < 3) ? fminf(loc[s], o) : fmaxf(loc[s], o);
        }
    }

    __shared__ float red[4][12];
    const int lane = threadIdx.x & 63;
    const int wid  = threadIdx.x >> 6;
    if (lane == 0) {
#pragma unroll
        for (int s = 0; s < 12; ++s) red[wid][s] = loc[s];
    }
    __syncthreads();

    if (threadIdx.x == 0) {
        float fin[12];
#pragma unroll
        for (int s = 0; s < 12; ++s) {
            const bool is_min = (s % 6) < 3;
            float v = red[0][s];
#pragma unroll
            for (int w = 1; w < 4; ++w)
                v = is_min ? fminf(v, red[w][s]) : fmaxf(v, red[w][s]);
            fin[s] = v;
        }
        const float inv_fx = 1.0f / intr[0], inv_fy = 1.0f / intr[1];
        float sx = (fin[3]  - fin[0]) * inv_fx;
        float sy = (fin[4]  - fin[1]) * inv_fy;
        float sz =  fin[5]  - fin[2];
        float dx = (fin[9]  - fin[6]) * inv_fx;
        float dy = (fin[10] - fin[7]) * inv_fy;
        float dz =  fin[11] - fin[8];
        ratio_p[0] = sqrtf(sx*sx + sy*sy + sz*sz) /
                     sqrtf(dx*dx + dy*dy + dz*dz);   // plain store
        out[NPIX] = 1.0f;  // std
    }
}

// Stage 3: pure streaming scale. dense is L3-warm from k1; nontemporal
// stores keep the output from evicting inputs (next replay's k1 benefits).
__global__ __launch_bounds__(BT) void scale_kernel(
    const float* __restrict__ dense,
    const float* __restrict__ ratio_p,
    float* __restrict__ out)
{
    const int tid = blockIdx.x * BT + threadIdx.x;
    const f32x4* d4 = (const f32x4*)dense;

    // dense loads in flight before the ratio pickup
    f32x4 v0 = d4[tid];
    f32x4 v1 = d4[tid + NB2 * BT];

    __shared__ float rs;
    if (threadIdx.x == 0) rs = ratio_p[0];   // plain load; kernel boundary ordered
    __syncthreads();
    const float r = rs;

    f32x4* o4 = (f32x4*)out;
    f32x4 r0 = v0 * r;
    f32x4 r1 = v1 * r;
    __builtin_nontemporal_store(r0, &o4[tid]);
    __builtin_nontemporal_store(r1, &o4[tid + NB2 * BT]);
}

extern "C" void kernel_launch(void* const* d_in, const int* in_sizes, int n_in,
                              void* d_out, int out_size, void* d_ws, size_t ws_size,
                              hipStream_t stream) {
    const float* dense  = (const float*)d_in[0];  // depth_estimations
    const float* sparse = (const float*)d_in[1];  // sparse_depths
    const int*   mask   = (const int*)d_in[2];    // sparse_depth_masks
    const float* intr   = (const float*)d_in[3];  // intrinsics

    float* out   = (float*)d_out;
    float* ws_f  = (float*)d_ws;
    float* ratio = ws_f + 12 * NB1;

    reduce_bbox_kernel<<<NB1, BT, 0, stream>>>(dense, sparse, mask, intr, ws_f);
    finalize_kernel<<<1, BT, 0, stream>>>(ws_f, intr, ratio, out);
    scale_kernel<<<NB2, BT, 0, stream>>>(dense, ratio, out);
}